// Round 27
// baseline (929.352 us; speedup 1.0000x reference)
//
#include <hip/hip_runtime.h>
#include <hip/hip_bf16.h>
#include <math.h>

#define NPTS    16384
#define DIM     128
#define KSEL    16
#define TSEL    18      // per-scanner top list (worst-case guarantee)
#define RPB     32      // rows per block (kernel S)
#define THREADS 256
#define QSEL    20      // per-(row,quarter) pruned candidates
#define NQ      4       // column quarters
#define NRC     (NQ * QSEL)        // 80 rescored candidates per row
#define SKQ     145                // LDS f32 stride per row (8*18 + pad)
#define NC      (8 * TSEL)         // 144 (R26 fallback)
#define CSTRIDE 145
#define RESC    32                 // R26 fallback prune
#define IDXMASK 0x3FFFu

typedef float f32x4  __attribute__((ext_vector_type(4)));
typedef short bf16x8 __attribute__((ext_vector_type(8)));

__device__ __forceinline__ unsigned short f2b(float f) {
    __hip_bfloat16 h = __float2bfloat16(f);   // RTNE
    return *(unsigned short*)&h;
}

#define MED3_LADDER(bv, val)                                   \
    do {                                                       \
        _Pragma("unroll")                                      \
        for (int k = TSEL - 1; k >= 1; --k)                    \
            bv[k] = fminf(bv[k], fmaxf(bv[k - 1], (val)));     \
        bv[0] = fminf(bv[0], (val));                           \
    } while (0)

// pack candidate index into low 14 mantissa bits (validated R25/R26)
__device__ __forceinline__ float packkey(float val, int jg) {
    const unsigned int u =
        (__float_as_uint(val) & 0xFFFFC000u) | (unsigned int)(jg & 0x3FFF);
    return __uint_as_float(u);
}

// BIT-EXACT numpy f32 pairwise-sum of x*x (AVX512 path) — validated R9.
__device__ __forceinline__ float np_sq_avx512(const float* __restrict__ x) {
    float s[16];
    #pragma unroll
    for (int L = 0; L < 16; ++L) {
        const float m0 = __fmul_rn(x[  0 + L], x[  0 + L]);
        const float m1 = __fmul_rn(x[ 16 + L], x[ 16 + L]);
        const float m2 = __fmul_rn(x[ 32 + L], x[ 32 + L]);
        const float m3 = __fmul_rn(x[ 48 + L], x[ 48 + L]);
        const float m4 = __fmul_rn(x[ 64 + L], x[ 64 + L]);
        const float m5 = __fmul_rn(x[ 80 + L], x[ 80 + L]);
        const float m6 = __fmul_rn(x[ 96 + L], x[ 96 + L]);
        const float m7 = __fmul_rn(x[112 + L], x[112 + L]);
        s[L] = __fadd_rn(
            __fadd_rn(__fadd_rn(m0, m1), __fadd_rn(m2, m3)),
            __fadd_rn(__fadd_rn(m4, m5), __fadd_rn(m6, m7)));
    }
    float u[8];
    #pragma unroll
    for (int i = 0; i < 8; ++i) u[i] = __fadd_rn(s[i], s[i + 8]);
    float v[4];
    #pragma unroll
    for (int i = 0; i < 4; ++i) v[i] = __fadd_rn(u[i], u[i + 4]);
    return __fadd_rn(__fadd_rn(v[0], v[2]), __fadd_rn(v[1], v[3]));
}

// scan-phase sq (capture key only)
__device__ __forceinline__ float scan_sq(const float* __restrict__ xp) {
    const float4* x4 = (const float4*)xp;
    float a0 = 0.f, a1 = 0.f, a2 = 0.f, a3 = 0.f;
    #pragma unroll
    for (int g = 0; g < 32; ++g) {
        const float4 b = x4[g];
        a0 += b.x * b.x; a1 += b.y * b.y;
        a2 += b.z * b.z; a3 += b.w * b.w;
    }
    return (a0 + a1) + (a2 + a3);
}

__global__ __launch_bounds__(256)
void sq_kernel(const float* __restrict__ X, float* __restrict__ sqws) {
    const int j = blockIdx.x * 256 + threadIdx.x;
    sqws[j] = 0.5f * scan_sq(X + (size_t)j * DIM);
}

__global__ __launch_bounds__(256)
void cvt_kernel(const float* __restrict__ X, unsigned short* __restrict__ Xb) {
    const size_t i = ((size_t)blockIdx.x * 256 + threadIdx.x) * 8;
    const float4 v0 = *(const float4*)(X + i);
    const float4 v1 = *(const float4*)(X + i + 4);
    ushort4 o0, o1;
    o0.x = f2b(v0.x); o0.y = f2b(v0.y); o0.z = f2b(v0.z); o0.w = f2b(v0.w);
    o1.x = f2b(v1.x); o1.y = f2b(v1.y); o1.z = f2b(v1.z); o1.w = f2b(v1.w);
    *(ushort4*)(Xb + i) = o0;
    *(ushort4*)(Xb + i + 4) = o1;
}

// ---- Kernel S: quarter-column packed scan, (256,3) for 3 waves/SIMD ----
// Block = 32 rows x 1 column quarter. Waves: 2 row-groups x 2 streams of
// 2048 cands; scanner = lane-group over 512 cands (TSEL=18 worst-case OK).
// Lean state (no bi, no prefetch, no rescore) targets the 84-reg cap.
__global__ __launch_bounds__(THREADS, 3)
void scan_q(const float* __restrict__ sqws,
            const unsigned short* __restrict__ Xb,
            unsigned short* __restrict__ candw) {
    __shared__ float sk[RPB * SKQ];   // 18560 B

    const int tid  = threadIdx.x;
    const int w    = tid >> 6;
    const int l    = tid & 63;
    const int lg   = l >> 4;
    const int l15  = l & 15;
    const int rg   = w >> 1;          // row-group 0..1
    const int st   = w & 1;           // stream-in-quarter 0..1
    const int rb   = blockIdx.x >> 2;
    const int qq   = blockIdx.x & 3;  // quarter
    const int rloc = rg * 16 + l15;
    const int grow = rb * RPB + rloc;
    const int colbase = qq * (NPTS / 4) + st * (NPTS / 8);
    const int sid  = st * 4 + lg;     // scanner 0..7

    // B fragments: NEGATED query row (validated R13+)
    bf16x8 nb[4];
    {
        const unsigned short* xr = Xb + (size_t)grow * DIM + lg * 8;
        #pragma unroll
        for (int m = 0; m < 4; ++m) {
            union { bf16x8 h; uint4 u; } t;
            t.h = *(const bf16x8*)(xr + m * 32);
            t.u.x ^= 0x80008000u; t.u.y ^= 0x80008000u;
            t.u.z ^= 0x80008000u; t.u.w ^= 0x80008000u;
            nb[m] = t.h;
        }
    }

    float bv[TSEL];
    #pragma unroll
    for (int k = 0; k < TSEL; ++k) bv[k] = 3.0e38f;
    {
        const unsigned short* ap = Xb + (size_t)(colbase + l15) * DIM + lg * 8;
        #pragma unroll 1
        for (int t = 0; t < (NPTS / 8) / 16; ++t) {   // 128 tiles
            const int cb = colbase + t * 16;
            const bf16x8 a0 = *(const bf16x8*)(ap);
            const bf16x8 a1 = *(const bf16x8*)(ap + 32);
            const bf16x8 a2 = *(const bf16x8*)(ap + 64);
            const bf16x8 a3 = *(const bf16x8*)(ap + 96);
            ap += 16 * DIM;
            f32x4 acc1 = *(const f32x4*)&sqws[cb + lg * 4];
            f32x4 acc2 = {0.f, 0.f, 0.f, 0.f};
            acc1 = __builtin_amdgcn_mfma_f32_16x16x32_bf16(a0, nb[0], acc1, 0, 0, 0);
            acc2 = __builtin_amdgcn_mfma_f32_16x16x32_bf16(a2, nb[2], acc2, 0, 0, 0);
            acc1 = __builtin_amdgcn_mfma_f32_16x16x32_bf16(a1, nb[1], acc1, 0, 0, 0);
            acc2 = __builtin_amdgcn_mfma_f32_16x16x32_bf16(a3, nb[3], acc2, 0, 0, 0);
            #pragma unroll
            for (int r = 0; r < 4; ++r) {
                const float p = packkey(acc1[r] + acc2[r], cb + lg * 4 + r);
                MED3_LADDER(bv, p);
            }
        }
    }

    // dump sorted per-scanner packed keys
    #pragma unroll
    for (int k = 0; k < TSEL; ++k)
        sk[rloc * SKQ + sid * TSEL + k] = bv[k];
    __syncthreads();

    // per-row 8-way sorted merge: pop QSEL smallest; write u16 indices to ws
    if (tid < RPB) {
        const int base = tid * SKQ;
        const int row = rb * RPB + tid;
        unsigned short* po = candw + ((size_t)row * NQ + qq) * QSEL;
        int head[8];
        #pragma unroll
        for (int s2 = 0; s2 < 8; ++s2) head[s2] = 0;
        for (int m = 0; m < QSEL; ++m) {
            float best = 3.0e38f; int bs = 0;
            #pragma unroll
            for (int s2 = 0; s2 < 8; ++s2) {
                const float v = (head[s2] < TSEL)
                    ? sk[base + s2 * TSEL + head[s2]] : 3.0e38f;
                if (v < best) { best = v; bs = s2; }
            }
            po[m] = (unsigned short)(__float_as_uint(best) & IDXMASK);
            #pragma unroll
            for (int s2 = 0; s2 < 8; ++s2) head[s2] += (s2 == bs) ? 1 : 0;
        }
    }
}

// ---- Kernel R: np-exact rescore of the 80 row candidates + top-16 ----
__global__ __launch_bounds__(THREADS)
void rescore_f(const float* __restrict__ X,
               const unsigned short* __restrict__ candw,
               int* __restrict__ out) {
    __shared__ unsigned long long ek[4][NRC];   // 2560 B

    const int tid  = threadIdx.x;
    const int rw   = tid >> 6;        // row-in-block 0..3
    const int lane = tid & 63;
    const int row  = blockIdx.x * 4 + rw;

    const float* xip = X + (size_t)row * DIM;
    const float4* xi4g = (const float4*)xip;
    const float sqi32 = np_sq_avx512(xip);

    #pragma unroll 1
    for (int m = lane; m < NRC; m += 64) {
        const int j = (int)candw[(size_t)row * NRC + m];
        unsigned long long key;
        if (j == row) {
            key = 0xFFFFFFFFFFFFFFFFULL;              // self: excluded
        } else {
            const float* xjp = X + (size_t)j * DIM;
            const float4* xj = (const float4*)xjp;
            const float sqj32 = np_sq_avx512(xjp);
            float cacc = 0.f;
            #pragma unroll
            for (int g = 0; g < 32; ++g) {
                const float4 a = xi4g[g], b = xj[g];
                cacc = __fmaf_rn(a.x, b.x, cacc);
                cacc = __fmaf_rn(a.y, b.y, cacc);
                cacc = __fmaf_rn(a.z, b.z, cacc);
                cacc = __fmaf_rn(a.w, b.w, cacc);
            }
            float d2c = __fsub_rn(__fadd_rn(sqi32, sqj32),
                                  __fmul_rn(2.0f, cacc));
            if (d2c < 0.0f) d2c = 0.0f;
            const float dist32 = sqrtf(d2c);          // f32 sqrt, correct rnd
            key = ((unsigned long long)__float_as_uint(dist32) << 32)
                  | (unsigned int)j;
        }
        ek[rw][m] = key;
    }
    __syncthreads();

    if (lane == 0) {
        for (int m = 0; m < KSEL; ++m) {
            unsigned long long best = 0xFFFFFFFFFFFFFFFFULL; int bc = 0;
            for (int c2 = 0; c2 < NRC; ++c2) {
                const unsigned long long v = ek[rw][c2];
                if (v < best) { best = v; bc = c2; }
            }
            out[(size_t)row * KSEL + m] = (int)(best & 0xFFFFFFFFULL);
            ek[rw][bc] = 0xFFFFFFFFFFFFFFFFULL;
        }
    }
}

// ---- fallback: R26 knn_packed (proven 607us) ----
__global__ __launch_bounds__(THREADS, 2)
void knn_packed(const float* __restrict__ X, const float* __restrict__ sqws,
                const unsigned short* __restrict__ Xb, int* __restrict__ out) {
    __shared__ __align__(16) char smem[30848];
    float*              sk = (float*)smem;
    unsigned int*       ci = (unsigned int*)(smem + 18560);
    unsigned long long* ek = (unsigned long long*)(smem + 22656);

    const int tid  = threadIdx.x;
    const int w    = tid >> 6;
    const int l    = tid & 63;
    const int lg   = l >> 4;
    const int l15  = l & 15;
    const int rloc = (w >> 1) * 16 + l15;
    const int grow = blockIdx.x * RPB + rloc;
    const int colbase = (w & 1) * (NPTS / 2);
    const int sid = (w & 1) * 4 + lg;

    bf16x8 nb[4];
    {
        const unsigned short* xr = Xb + (size_t)grow * DIM + lg * 8;
        #pragma unroll
        for (int m = 0; m < 4; ++m) {
            union { bf16x8 h; uint4 u; } t;
            t.h = *(const bf16x8*)(xr + m * 32);
            t.u.x ^= 0x80008000u; t.u.y ^= 0x80008000u;
            t.u.z ^= 0x80008000u; t.u.w ^= 0x80008000u;
            nb[m] = t.h;
        }
    }

    float bv[TSEL];
    #pragma unroll
    for (int k = 0; k < TSEL; ++k) bv[k] = 3.0e38f;
    {
        const unsigned short* ap = Xb + (size_t)(colbase + l15) * DIM + lg * 8;
        #pragma unroll 1
        for (int t = 0; t < (NPTS / 2) / 16; t += 2) {
            const int cb = colbase + t * 16;
            const bf16x8 a0 = *(const bf16x8*)(ap);
            const bf16x8 a1 = *(const bf16x8*)(ap + 32);
            const bf16x8 a2 = *(const bf16x8*)(ap + 64);
            const bf16x8 a3 = *(const bf16x8*)(ap + 96);
            const bf16x8 b0 = *(const bf16x8*)(ap + 16 * DIM);
            const bf16x8 b1 = *(const bf16x8*)(ap + 16 * DIM + 32);
            const bf16x8 b2 = *(const bf16x8*)(ap + 16 * DIM + 64);
            const bf16x8 b3 = *(const bf16x8*)(ap + 16 * DIM + 96);
            ap += 32 * DIM;
            f32x4 aA1 = *(const f32x4*)&sqws[cb + lg * 4];
            f32x4 aA2 = {0.f, 0.f, 0.f, 0.f};
            f32x4 aB1 = *(const f32x4*)&sqws[cb + 16 + lg * 4];
            f32x4 aB2 = {0.f, 0.f, 0.f, 0.f};
            aA1 = __builtin_amdgcn_mfma_f32_16x16x32_bf16(a0, nb[0], aA1, 0, 0, 0);
            aA2 = __builtin_amdgcn_mfma_f32_16x16x32_bf16(a2, nb[2], aA2, 0, 0, 0);
            aB1 = __builtin_amdgcn_mfma_f32_16x16x32_bf16(b0, nb[0], aB1, 0, 0, 0);
            aB2 = __builtin_amdgcn_mfma_f32_16x16x32_bf16(b2, nb[2], aB2, 0, 0, 0);
            aA1 = __builtin_amdgcn_mfma_f32_16x16x32_bf16(a1, nb[1], aA1, 0, 0, 0);
            aA2 = __builtin_amdgcn_mfma_f32_16x16x32_bf16(a3, nb[3], aA2, 0, 0, 0);
            aB1 = __builtin_amdgcn_mfma_f32_16x16x32_bf16(b1, nb[1], aB1, 0, 0, 0);
            aB2 = __builtin_amdgcn_mfma_f32_16x16x32_bf16(b3, nb[3], aB2, 0, 0, 0);
            #pragma unroll
            for (int r = 0; r < 4; ++r) {
                const float pA = packkey(aA1[r] + aA2[r], cb + lg * 4 + r);
                MED3_LADDER(bv, pA);
            }
            #pragma unroll
            for (int r = 0; r < 4; ++r) {
                const float pB = packkey(aB1[r] + aB2[r], cb + 16 + lg * 4 + r);
                MED3_LADDER(bv, pB);
            }
        }
    }

    #pragma unroll
    for (int k = 0; k < TSEL; ++k)
        sk[rloc * SKQ + sid * TSEL + k] = bv[k];
    __syncthreads();

    if (tid < RPB) {
        const int base = tid * SKQ;
        int head[8];
        #pragma unroll
        for (int s2 = 0; s2 < 8; ++s2) head[s2] = 0;
        for (int m = 0; m < RESC; ++m) {
            float best = 3.0e38f; int bs = 0;
            #pragma unroll
            for (int s2 = 0; s2 < 8; ++s2) {
                const float v = (head[s2] < TSEL)
                    ? sk[base + s2 * TSEL + head[s2]] : 3.0e38f;
                if (v < best) { best = v; bs = s2; }
            }
            ci[tid * RESC + m] = __float_as_uint(best) & IDXMASK;
            #pragma unroll
            for (int s2 = 0; s2 < 8; ++s2) head[s2] += (s2 == bs) ? 1 : 0;
        }
    }
    __syncthreads();

    float4 xi4[32];
    {
        const float4* xr = (const float4*)(X + (size_t)grow * DIM);
        #pragma unroll
        for (int g = 0; g < 32; ++g) xi4[g] = xr[g];
    }
    const float sqi32 = np_sq_avx512(X + (size_t)grow * DIM);

    #pragma unroll 1
    for (int q = 0; q < RESC / 8; ++q) {
        const int m = sid * (RESC / 8) + q;
        const int j = (int)ci[rloc * RESC + m];
        unsigned long long key;
        if (j == grow) {
            key = 0xFFFFFFFFFFFFFFFFULL;
        } else {
            const float* xjp = X + (size_t)j * DIM;
            const float4* xj = (const float4*)xjp;
            const float sqj32 = np_sq_avx512(xjp);
            float cacc = 0.f;
            #pragma unroll
            for (int g = 0; g < 32; ++g) {
                const float4 a = xi4[g], b = xj[g];
                cacc = __fmaf_rn(a.x, b.x, cacc);
                cacc = __fmaf_rn(a.y, b.y, cacc);
                cacc = __fmaf_rn(a.z, b.z, cacc);
                cacc = __fmaf_rn(a.w, b.w, cacc);
            }
            float d2c = __fsub_rn(__fadd_rn(sqi32, sqj32),
                                  __fmul_rn(2.0f, cacc));
            if (d2c < 0.0f) d2c = 0.0f;
            const float dist32 = sqrtf(d2c);
            key = ((unsigned long long)__float_as_uint(dist32) << 32)
                  | (unsigned int)j;
        }
        ek[rloc * RESC + m] = key;
    }
    __syncthreads();

    if (tid < RPB) {
        const int base = tid * RESC;
        const int i = blockIdx.x * RPB + tid;
        for (int m = 0; m < KSEL; ++m) {
            unsigned long long best = 0xFFFFFFFFFFFFFFFFULL; int bc = 0;
            for (int c2 = 0; c2 < RESC; ++c2) {
                const unsigned long long v = ek[base + c2];
                if (v < best) { best = v; bc = c2; }
            }
            out[(size_t)i * KSEL + m] = (int)(best & 0xFFFFFFFFULL);
            ek[base + bc] = 0xFFFFFFFFFFFFFFFFULL;
        }
    }
}

// ---- fallback monolith (R14 verbatim, no workspace) ----
__global__ __launch_bounds__(THREADS, 2)
void knn_mono(const float* __restrict__ X, int* __restrict__ out) {
    __shared__ __align__(16) char smem[NPTS * 4];
    float* sqh = (float*)smem;
    unsigned long long* keys = (unsigned long long*)smem;
    const int tid = threadIdx.x;
    const int w = tid >> 6, l = tid & 63, lg = l >> 4, l15 = l & 15;
    const int rloc = (w >> 1) * 16 + l15;
    const int grow = blockIdx.x * RPB + rloc;
    const int colbase = (w & 1) * (NPTS / 2);
    const int s = (w & 1) * 4 + lg;
    #pragma unroll 1
    for (int q = 0; q < NPTS / THREADS; ++q) {
        const int j = tid + THREADS * q;
        sqh[j] = 0.5f * scan_sq(X + (size_t)j * DIM);
    }
    __syncthreads();
    bf16x8 nb[4];
    {
        const float* xr = X + (size_t)grow * DIM + lg * 8;
        #pragma unroll
        for (int m = 0; m < 4; ++m) {
            bf16x8 h;
            #pragma unroll
            for (int e = 0; e < 8; ++e) h[e] = (short)f2b(-xr[m * 32 + e]);
            nb[m] = h;
        }
    }
    float bv[TSEL]; int bi[TSEL];
    #pragma unroll
    for (int k = 0; k < TSEL; ++k) { bv[k] = 3.0e38f; bi[k] = 0; }
    const float* apf = X + (size_t)(colbase + l15) * DIM + lg * 8;
    #pragma unroll 1
    for (int t = 0; t < (NPTS / 2) / 16; ++t) {
        const int cb = colbase + t * 16;
        bf16x8 a0, a1, a2, a3;
        #pragma unroll
        for (int e = 0; e < 8; ++e) {
            a0[e] = (short)f2b(apf[e]);
            a1[e] = (short)f2b(apf[32 + e]);
            a2[e] = (short)f2b(apf[64 + e]);
            a3[e] = (short)f2b(apf[96 + e]);
        }
        apf += 16 * DIM;
        f32x4 acc = *(const f32x4*)&sqh[cb + lg * 4];
        acc = __builtin_amdgcn_mfma_f32_16x16x32_bf16(a0, nb[0], acc, 0, 0, 0);
        acc = __builtin_amdgcn_mfma_f32_16x16x32_bf16(a1, nb[1], acc, 0, 0, 0);
        acc = __builtin_amdgcn_mfma_f32_16x16x32_bf16(a2, nb[2], acc, 0, 0, 0);
        acc = __builtin_amdgcn_mfma_f32_16x16x32_bf16(a3, nb[3], acc, 0, 0, 0);
        #pragma unroll
        for (int r = 0; r < 4; ++r) {
            const float val = acc[r];
            if (val < bv[TSEL - 1]) {
                const int jg = cb + lg * 4 + r;
                #pragma unroll
                for (int k = TSEL - 1; k >= 1; --k) {
                    const bool m1 = val < bv[k - 1];
                    const bool m2 = val < bv[k];
                    bv[k] = m1 ? bv[k - 1] : (m2 ? val : bv[k]);
                    bi[k] = m1 ? bi[k - 1] : (m2 ? jg  : bi[k]);
                }
                if (val < bv[0]) { bv[0] = val; bi[0] = jg; }
            }
        }
    }
    __syncthreads();
    float4 xi4[32];
    {
        const float4* xr = (const float4*)(X + (size_t)grow * DIM);
        #pragma unroll
        for (int g = 0; g < 32; ++g) xi4[g] = xr[g];
    }
    const float sqi32 = np_sq_avx512(X + (size_t)grow * DIM);
    #pragma unroll
    for (int k = 0; k < TSEL; ++k) {
        const int j = bi[k];
        unsigned long long key;
        if (j == grow) {
            key = 0xFFFFFFFFFFFFFFFFULL;
        } else {
            const float* xjp = X + (size_t)j * DIM;
            const float4* xj = (const float4*)xjp;
            const float sqj32 = np_sq_avx512(xjp);
            float cacc = 0.f;
            #pragma unroll
            for (int g = 0; g < 32; ++g) {
                const float4 a = xi4[g], b = xj[g];
                cacc = __fmaf_rn(a.x, b.x, cacc);
                cacc = __fmaf_rn(a.y, b.y, cacc);
                cacc = __fmaf_rn(a.z, b.z, cacc);
                cacc = __fmaf_rn(a.w, b.w, cacc);
            }
            float d2c = __fsub_rn(__fadd_rn(sqi32, sqj32),
                                  __fmul_rn(2.0f, cacc));
            if (d2c < 0.0f) d2c = 0.0f;
            const float dist32 = sqrtf(d2c);
            key = ((unsigned long long)__float_as_uint(dist32) << 32)
                  | (unsigned int)j;
        }
        keys[rloc * CSTRIDE + s * TSEL + k] = key;
    }
    __syncthreads();
    if (tid < RPB) {
        const int base = tid * CSTRIDE;
        const int i = blockIdx.x * RPB + tid;
        for (int m = 0; m < KSEL; ++m) {
            unsigned long long best = 0xFFFFFFFFFFFFFFFFULL; int bc = 0;
            for (int c2 = 0; c2 < NC; ++c2) {
                const unsigned long long v = keys[base + c2];
                if (v < best) { best = v; bc = c2; }
            }
            out[(size_t)i * KSEL + m] = (int)(best & 0xFFFFFFFFULL);
            keys[base + bc] = 0xFFFFFFFFFFFFFFFFULL;
        }
    }
}

extern "C" void kernel_launch(void* const* d_in, const int* in_sizes, int n_in,
                              void* d_out, int out_size, void* d_ws, size_t ws_size,
                              hipStream_t stream) {
    (void)in_sizes; (void)n_in; (void)out_size;
    const float* X = (const float*)d_in[0];
    int* out = (int*)d_out;
    const size_t sqB   = (size_t)NPTS * 4;                 // 64 KB
    const size_t xbB   = (size_t)NPTS * DIM * 2;           // 4.19 MB
    const size_t candB = (size_t)NPTS * NRC * 2;           // 2.62 MB
    float* sqws = (float*)d_ws;
    unsigned short* Xb = (unsigned short*)((char*)d_ws + sqB);
    unsigned short* candw = (unsigned short*)((char*)d_ws + sqB + xbB);
    if (ws_size >= sqB + xbB + candB) {                    // 6.88 MB <= 8.45 proven
        sq_kernel<<<dim3(NPTS / 256), dim3(256), 0, stream>>>(X, sqws);
        cvt_kernel<<<dim3(NPTS * DIM / 8 / 256), dim3(256), 0, stream>>>(X, Xb);
        scan_q<<<dim3((NPTS / RPB) * NQ), dim3(THREADS), 0, stream>>>(sqws, Xb, candw);
        rescore_f<<<dim3(NPTS / 4), dim3(THREADS), 0, stream>>>(X, candw, out);
    } else if (ws_size >= sqB + xbB) {
        sq_kernel<<<dim3(NPTS / 256), dim3(256), 0, stream>>>(X, sqws);
        cvt_kernel<<<dim3(NPTS * DIM / 8 / 256), dim3(256), 0, stream>>>(X, Xb);
        knn_packed<<<dim3(NPTS / RPB), dim3(THREADS), 0, stream>>>(X, sqws, Xb, out);
    } else {
        knn_mono<<<dim3(NPTS / RPB), dim3(THREADS), 0, stream>>>(X, out);
    }
}

// Round 28
// 750.711 us; speedup vs baseline: 1.2380x; 1.2380x over previous
//
#include <hip/hip_runtime.h>
#include <hip/hip_bf16.h>
#include <math.h>

#define NPTS    16384
#define DIM     128
#define KSEL    16
#define TSEL    10      // per-scanner top list (probabilistic margin, R28)
#define RPB     32      // rows per block (kernel S)
#define THREADS 256
#define QSEL    16      // per-(row,quarter) pruned candidates (1 lane each)
#define NQ      4       // column quarters
#define NRC     (NQ * QSEL)        // 64 rescored candidates per row
#define SKQ     81                 // LDS f32 stride per row (8*10 + pad)
#define TSEL6   18      // fallback kernels keep the deterministic margin
#define NC      (8 * TSEL6)        // 144 (fallback)
#define CSTRIDE 145
#define RESC    32
#define SKQ6    145
#define IDXMASK 0x3FFFu

typedef float f32x4  __attribute__((ext_vector_type(4)));
typedef short bf16x8 __attribute__((ext_vector_type(8)));

__device__ __forceinline__ unsigned short f2b(float f) {
    __hip_bfloat16 h = __float2bfloat16(f);   // RTNE
    return *(unsigned short*)&h;
}

#define MED3_LADDER_N(bv, val, N)                              \
    do {                                                       \
        _Pragma("unroll")                                      \
        for (int k = (N) - 1; k >= 1; --k)                     \
            bv[k] = fminf(bv[k], fmaxf(bv[k - 1], (val)));     \
        bv[0] = fminf(bv[0], (val));                           \
    } while (0)

// pack candidate index into low 14 mantissa bits (validated R25/R26)
__device__ __forceinline__ float packkey(float val, int jg) {
    const unsigned int u =
        (__float_as_uint(val) & 0xFFFFC000u) | (unsigned int)(jg & 0x3FFF);
    return __uint_as_float(u);
}

// BIT-EXACT numpy f32 pairwise-sum of x*x (AVX512 path) — validated R9.
__device__ __forceinline__ float np_sq_avx512(const float* __restrict__ x) {
    float s[16];
    #pragma unroll
    for (int L = 0; L < 16; ++L) {
        const float m0 = __fmul_rn(x[  0 + L], x[  0 + L]);
        const float m1 = __fmul_rn(x[ 16 + L], x[ 16 + L]);
        const float m2 = __fmul_rn(x[ 32 + L], x[ 32 + L]);
        const float m3 = __fmul_rn(x[ 48 + L], x[ 48 + L]);
        const float m4 = __fmul_rn(x[ 64 + L], x[ 64 + L]);
        const float m5 = __fmul_rn(x[ 80 + L], x[ 80 + L]);
        const float m6 = __fmul_rn(x[ 96 + L], x[ 96 + L]);
        const float m7 = __fmul_rn(x[112 + L], x[112 + L]);
        s[L] = __fadd_rn(
            __fadd_rn(__fadd_rn(m0, m1), __fadd_rn(m2, m3)),
            __fadd_rn(__fadd_rn(m4, m5), __fadd_rn(m6, m7)));
    }
    float u[8];
    #pragma unroll
    for (int i = 0; i < 8; ++i) u[i] = __fadd_rn(s[i], s[i + 8]);
    float v[4];
    #pragma unroll
    for (int i = 0; i < 4; ++i) v[i] = __fadd_rn(u[i], u[i + 4]);
    return __fadd_rn(__fadd_rn(v[0], v[2]), __fadd_rn(v[1], v[3]));
}

// scan-phase sq (capture key only)
__device__ __forceinline__ float scan_sq(const float* __restrict__ xp) {
    const float4* x4 = (const float4*)xp;
    float a0 = 0.f, a1 = 0.f, a2 = 0.f, a3 = 0.f;
    #pragma unroll
    for (int g = 0; g < 32; ++g) {
        const float4 b = x4[g];
        a0 += b.x * b.x; a1 += b.y * b.y;
        a2 += b.z * b.z; a3 += b.w * b.w;
    }
    return (a0 + a1) + (a2 + a3);
}

__global__ __launch_bounds__(256)
void sq_kernel(const float* __restrict__ X, float* __restrict__ sqws) {
    const int j = blockIdx.x * 256 + threadIdx.x;
    sqws[j] = 0.5f * scan_sq(X + (size_t)j * DIM);
}

__global__ __launch_bounds__(256)
void cvt_kernel(const float* __restrict__ X, unsigned short* __restrict__ Xb) {
    const size_t i = ((size_t)blockIdx.x * 256 + threadIdx.x) * 8;
    const float4 v0 = *(const float4*)(X + i);
    const float4 v1 = *(const float4*)(X + i + 4);
    ushort4 o0, o1;
    o0.x = f2b(v0.x); o0.y = f2b(v0.y); o0.z = f2b(v0.z); o0.w = f2b(v0.w);
    o1.x = f2b(v1.x); o1.y = f2b(v1.y); o1.z = f2b(v1.z); o1.w = f2b(v1.w);
    *(ushort4*)(Xb + i) = o0;
    *(ushort4*)(Xb + i + 4) = o1;
}

// ---- Kernel S: quarter-column packed scan, (256,3), TSEL=10 + prefetch ----
__global__ __launch_bounds__(THREADS, 3)
void scan_q(const float* __restrict__ sqws,
            const unsigned short* __restrict__ Xb,
            unsigned short* __restrict__ candw) {
    __shared__ float sk[RPB * SKQ];   // 10368 B

    const int tid  = threadIdx.x;
    const int w    = tid >> 6;
    const int l    = tid & 63;
    const int lg   = l >> 4;
    const int l15  = l & 15;
    const int rg   = w >> 1;          // row-group 0..1
    const int st   = w & 1;           // stream-in-quarter 0..1
    const int rb   = blockIdx.x >> 2;
    const int qq   = blockIdx.x & 3;  // quarter
    const int rloc = rg * 16 + l15;
    const int grow = rb * RPB + rloc;
    const int colbase = qq * (NPTS / 4) + st * (NPTS / 8);
    const int sid  = st * 4 + lg;     // scanner 0..7

    // B fragments: NEGATED query row (validated R13+)
    bf16x8 nb[4];
    {
        const unsigned short* xr = Xb + (size_t)grow * DIM + lg * 8;
        #pragma unroll
        for (int m = 0; m < 4; ++m) {
            union { bf16x8 h; uint4 u; } t;
            t.h = *(const bf16x8*)(xr + m * 32);
            t.u.x ^= 0x80008000u; t.u.y ^= 0x80008000u;
            t.u.z ^= 0x80008000u; t.u.w ^= 0x80008000u;
            nb[m] = t.h;
        }
    }

    float bv[TSEL];
    #pragma unroll
    for (int k = 0; k < TSEL; ++k) bv[k] = 3.0e38f;
    {
        const unsigned short* ap = Xb + (size_t)(colbase + l15) * DIM + lg * 8;
        bf16x8 c0 = *(const bf16x8*)(ap);
        bf16x8 c1 = *(const bf16x8*)(ap + 32);
        bf16x8 c2 = *(const bf16x8*)(ap + 64);
        bf16x8 c3 = *(const bf16x8*)(ap + 96);
        #pragma unroll 1
        for (int t = 0; t < (NPTS / 8) / 16; ++t) {   // 128 tiles
            const int cb = colbase + t * 16;
            const unsigned short* apn =
                (t + 1 < (NPTS / 8) / 16) ? ap + 16 * DIM : ap;
            const bf16x8 n0 = *(const bf16x8*)(apn);
            const bf16x8 n1 = *(const bf16x8*)(apn + 32);
            const bf16x8 n2 = *(const bf16x8*)(apn + 64);
            const bf16x8 n3 = *(const bf16x8*)(apn + 96);

            f32x4 acc1 = *(const f32x4*)&sqws[cb + lg * 4];
            f32x4 acc2 = {0.f, 0.f, 0.f, 0.f};
            acc1 = __builtin_amdgcn_mfma_f32_16x16x32_bf16(c0, nb[0], acc1, 0, 0, 0);
            acc2 = __builtin_amdgcn_mfma_f32_16x16x32_bf16(c2, nb[2], acc2, 0, 0, 0);
            acc1 = __builtin_amdgcn_mfma_f32_16x16x32_bf16(c1, nb[1], acc1, 0, 0, 0);
            acc2 = __builtin_amdgcn_mfma_f32_16x16x32_bf16(c3, nb[3], acc2, 0, 0, 0);
            #pragma unroll
            for (int r = 0; r < 4; ++r) {
                const float p = packkey(acc1[r] + acc2[r], cb + lg * 4 + r);
                MED3_LADDER_N(bv, p, TSEL);
            }
            c0 = n0; c1 = n1; c2 = n2; c3 = n3;
            ap = apn;
        }
    }

    // dump sorted per-scanner packed keys
    #pragma unroll
    for (int k = 0; k < TSEL; ++k)
        sk[rloc * SKQ + sid * TSEL + k] = bv[k];
    __syncthreads();

    // per-row 8-way sorted merge: pop QSEL smallest; u16 indices to ws
    if (tid < RPB) {
        const int base = tid * SKQ;
        const int row = rb * RPB + tid;
        unsigned short* po = candw + ((size_t)row * NQ + qq) * QSEL;
        int head[8];
        #pragma unroll
        for (int s2 = 0; s2 < 8; ++s2) head[s2] = 0;
        for (int m = 0; m < QSEL; ++m) {
            float best = 3.0e38f; int bs = 0;
            #pragma unroll
            for (int s2 = 0; s2 < 8; ++s2) {
                const float v = (head[s2] < TSEL)
                    ? sk[base + s2 * TSEL + head[s2]] : 3.0e38f;
                if (v < best) { best = v; bs = s2; }
            }
            po[m] = (unsigned short)(__float_as_uint(best) & IDXMASK);
            #pragma unroll
            for (int s2 = 0; s2 < 8; ++s2) head[s2] += (s2 == bs) ? 1 : 0;
        }
    }
}

// ---- Kernel R: one wave per row, one candidate per lane, shfl merge ----
__global__ __launch_bounds__(THREADS)
void rescore_f(const float* __restrict__ X,
               const unsigned short* __restrict__ candw,
               int* __restrict__ out) {
    const int tid  = threadIdx.x;
    const int rw   = tid >> 6;        // row-in-block 0..3
    const int lane = tid & 63;
    const int row  = blockIdx.x * 4 + rw;

    const float* xip = X + (size_t)row * DIM;
    const float4* xi4g = (const float4*)xip;
    const float sqi32 = np_sq_avx512(xip);

    // np-exact rescore of this lane's candidate (validated R9 formula)
    const int j = (int)candw[(size_t)row * NRC + lane];
    unsigned long long my;
    if (j == row) {
        my = 0xFFFFFFFFFFFFFFFFULL;                   // self: excluded
    } else {
        const float* xjp = X + (size_t)j * DIM;
        const float4* xj = (const float4*)xjp;
        const float sqj32 = np_sq_avx512(xjp);
        float cacc = 0.f;
        #pragma unroll
        for (int g = 0; g < 32; ++g) {
            const float4 a = xi4g[g], b = xj[g];
            cacc = __fmaf_rn(a.x, b.x, cacc);
            cacc = __fmaf_rn(a.y, b.y, cacc);
            cacc = __fmaf_rn(a.z, b.z, cacc);
            cacc = __fmaf_rn(a.w, b.w, cacc);
        }
        float d2c = __fsub_rn(__fadd_rn(sqi32, sqj32),
                              __fmul_rn(2.0f, cacc));
        if (d2c < 0.0f) d2c = 0.0f;
        const float dist32 = sqrtf(d2c);              // f32 sqrt, correct rnd
        my = ((unsigned long long)__float_as_uint(dist32) << 32)
             | (unsigned int)j;
    }

    // 16 rounds of 64-lane u64 min-reduce; keys unique (idx embedded)
    #pragma unroll 1
    for (int m = 0; m < KSEL; ++m) {
        unsigned long long mn = my;
        #pragma unroll
        for (int off = 32; off > 0; off >>= 1) {
            const unsigned long long o = __shfl_xor(mn, off, 64);
            mn = (o < mn) ? o : mn;
        }
        if (lane == 0)
            out[(size_t)row * KSEL + m] = (int)(mn & 0xFFFFFFFFULL);
        if (my == mn) my = 0xFFFFFFFFFFFFFFFFULL;     // remove picked
    }
}

// ---- fallback: R26 knn_packed (proven 607us; deterministic TSEL6=18) ----
__global__ __launch_bounds__(THREADS, 2)
void knn_packed(const float* __restrict__ X, const float* __restrict__ sqws,
                const unsigned short* __restrict__ Xb, int* __restrict__ out) {
    __shared__ __align__(16) char smem[30848];
    float*              sk = (float*)smem;
    unsigned int*       ci = (unsigned int*)(smem + 18560);
    unsigned long long* ek = (unsigned long long*)(smem + 22656);

    const int tid  = threadIdx.x;
    const int w    = tid >> 6;
    const int l    = tid & 63;
    const int lg   = l >> 4;
    const int l15  = l & 15;
    const int rloc = (w >> 1) * 16 + l15;
    const int grow = blockIdx.x * RPB + rloc;
    const int colbase = (w & 1) * (NPTS / 2);
    const int sid = (w & 1) * 4 + lg;

    bf16x8 nb[4];
    {
        const unsigned short* xr = Xb + (size_t)grow * DIM + lg * 8;
        #pragma unroll
        for (int m = 0; m < 4; ++m) {
            union { bf16x8 h; uint4 u; } t;
            t.h = *(const bf16x8*)(xr + m * 32);
            t.u.x ^= 0x80008000u; t.u.y ^= 0x80008000u;
            t.u.z ^= 0x80008000u; t.u.w ^= 0x80008000u;
            nb[m] = t.h;
        }
    }

    float bv[TSEL6];
    #pragma unroll
    for (int k = 0; k < TSEL6; ++k) bv[k] = 3.0e38f;
    {
        const unsigned short* ap = Xb + (size_t)(colbase + l15) * DIM + lg * 8;
        #pragma unroll 1
        for (int t = 0; t < (NPTS / 2) / 16; t += 2) {
            const int cb = colbase + t * 16;
            const bf16x8 a0 = *(const bf16x8*)(ap);
            const bf16x8 a1 = *(const bf16x8*)(ap + 32);
            const bf16x8 a2 = *(const bf16x8*)(ap + 64);
            const bf16x8 a3 = *(const bf16x8*)(ap + 96);
            const bf16x8 b0 = *(const bf16x8*)(ap + 16 * DIM);
            const bf16x8 b1 = *(const bf16x8*)(ap + 16 * DIM + 32);
            const bf16x8 b2 = *(const bf16x8*)(ap + 16 * DIM + 64);
            const bf16x8 b3 = *(const bf16x8*)(ap + 16 * DIM + 96);
            ap += 32 * DIM;
            f32x4 aA1 = *(const f32x4*)&sqws[cb + lg * 4];
            f32x4 aA2 = {0.f, 0.f, 0.f, 0.f};
            f32x4 aB1 = *(const f32x4*)&sqws[cb + 16 + lg * 4];
            f32x4 aB2 = {0.f, 0.f, 0.f, 0.f};
            aA1 = __builtin_amdgcn_mfma_f32_16x16x32_bf16(a0, nb[0], aA1, 0, 0, 0);
            aA2 = __builtin_amdgcn_mfma_f32_16x16x32_bf16(a2, nb[2], aA2, 0, 0, 0);
            aB1 = __builtin_amdgcn_mfma_f32_16x16x32_bf16(b0, nb[0], aB1, 0, 0, 0);
            aB2 = __builtin_amdgcn_mfma_f32_16x16x32_bf16(b2, nb[2], aB2, 0, 0, 0);
            aA1 = __builtin_amdgcn_mfma_f32_16x16x32_bf16(a1, nb[1], aA1, 0, 0, 0);
            aA2 = __builtin_amdgcn_mfma_f32_16x16x32_bf16(a3, nb[3], aA2, 0, 0, 0);
            aB1 = __builtin_amdgcn_mfma_f32_16x16x32_bf16(b1, nb[1], aB1, 0, 0, 0);
            aB2 = __builtin_amdgcn_mfma_f32_16x16x32_bf16(b3, nb[3], aB2, 0, 0, 0);
            #pragma unroll
            for (int r = 0; r < 4; ++r) {
                const float pA = packkey(aA1[r] + aA2[r], cb + lg * 4 + r);
                MED3_LADDER_N(bv, pA, TSEL6);
            }
            #pragma unroll
            for (int r = 0; r < 4; ++r) {
                const float pB = packkey(aB1[r] + aB2[r], cb + 16 + lg * 4 + r);
                MED3_LADDER_N(bv, pB, TSEL6);
            }
        }
    }

    #pragma unroll
    for (int k = 0; k < TSEL6; ++k)
        sk[rloc * SKQ6 + sid * TSEL6 + k] = bv[k];
    __syncthreads();

    if (tid < RPB) {
        const int base = tid * SKQ6;
        int head[8];
        #pragma unroll
        for (int s2 = 0; s2 < 8; ++s2) head[s2] = 0;
        for (int m = 0; m < RESC; ++m) {
            float best = 3.0e38f; int bs = 0;
            #pragma unroll
            for (int s2 = 0; s2 < 8; ++s2) {
                const float v = (head[s2] < TSEL6)
                    ? sk[base + s2 * TSEL6 + head[s2]] : 3.0e38f;
                if (v < best) { best = v; bs = s2; }
            }
            ci[tid * RESC + m] = __float_as_uint(best) & IDXMASK;
            #pragma unroll
            for (int s2 = 0; s2 < 8; ++s2) head[s2] += (s2 == bs) ? 1 : 0;
        }
    }
    __syncthreads();

    float4 xi4[32];
    {
        const float4* xr = (const float4*)(X + (size_t)grow * DIM);
        #pragma unroll
        for (int g = 0; g < 32; ++g) xi4[g] = xr[g];
    }
    const float sqi32 = np_sq_avx512(X + (size_t)grow * DIM);

    #pragma unroll 1
    for (int q = 0; q < RESC / 8; ++q) {
        const int m = sid * (RESC / 8) + q;
        const int j = (int)ci[rloc * RESC + m];
        unsigned long long key;
        if (j == grow) {
            key = 0xFFFFFFFFFFFFFFFFULL;
        } else {
            const float* xjp = X + (size_t)j * DIM;
            const float4* xj = (const float4*)xjp;
            const float sqj32 = np_sq_avx512(xjp);
            float cacc = 0.f;
            #pragma unroll
            for (int g = 0; g < 32; ++g) {
                const float4 a = xi4[g], b = xj[g];
                cacc = __fmaf_rn(a.x, b.x, cacc);
                cacc = __fmaf_rn(a.y, b.y, cacc);
                cacc = __fmaf_rn(a.z, b.z, cacc);
                cacc = __fmaf_rn(a.w, b.w, cacc);
            }
            float d2c = __fsub_rn(__fadd_rn(sqi32, sqj32),
                                  __fmul_rn(2.0f, cacc));
            if (d2c < 0.0f) d2c = 0.0f;
            const float dist32 = sqrtf(d2c);
            key = ((unsigned long long)__float_as_uint(dist32) << 32)
                  | (unsigned int)j;
        }
        ek[rloc * RESC + m] = key;
    }
    __syncthreads();

    if (tid < RPB) {
        const int base = tid * RESC;
        const int i = blockIdx.x * RPB + tid;
        for (int m = 0; m < KSEL; ++m) {
            unsigned long long best = 0xFFFFFFFFFFFFFFFFULL; int bc = 0;
            for (int c2 = 0; c2 < RESC; ++c2) {
                const unsigned long long v = ek[base + c2];
                if (v < best) { best = v; bc = c2; }
            }
            out[(size_t)i * KSEL + m] = (int)(best & 0xFFFFFFFFULL);
            ek[base + bc] = 0xFFFFFFFFFFFFFFFFULL;
        }
    }
}

// ---- fallback monolith (R14 verbatim, no workspace) ----
__global__ __launch_bounds__(THREADS, 2)
void knn_mono(const float* __restrict__ X, int* __restrict__ out) {
    __shared__ __align__(16) char smem[NPTS * 4];
    float* sqh = (float*)smem;
    unsigned long long* keys = (unsigned long long*)smem;
    const int tid = threadIdx.x;
    const int w = tid >> 6, l = tid & 63, lg = l >> 4, l15 = l & 15;
    const int rloc = (w >> 1) * 16 + l15;
    const int grow = blockIdx.x * RPB + rloc;
    const int colbase = (w & 1) * (NPTS / 2);
    const int s = (w & 1) * 4 + lg;
    #pragma unroll 1
    for (int q = 0; q < NPTS / THREADS; ++q) {
        const int j = tid + THREADS * q;
        sqh[j] = 0.5f * scan_sq(X + (size_t)j * DIM);
    }
    __syncthreads();
    bf16x8 nb[4];
    {
        const float* xr = X + (size_t)grow * DIM + lg * 8;
        #pragma unroll
        for (int m = 0; m < 4; ++m) {
            bf16x8 h;
            #pragma unroll
            for (int e = 0; e < 8; ++e) h[e] = (short)f2b(-xr[m * 32 + e]);
            nb[m] = h;
        }
    }
    float bv[TSEL6]; int bi[TSEL6];
    #pragma unroll
    for (int k = 0; k < TSEL6; ++k) { bv[k] = 3.0e38f; bi[k] = 0; }
    const float* apf = X + (size_t)(colbase + l15) * DIM + lg * 8;
    #pragma unroll 1
    for (int t = 0; t < (NPTS / 2) / 16; ++t) {
        const int cb = colbase + t * 16;
        bf16x8 a0, a1, a2, a3;
        #pragma unroll
        for (int e = 0; e < 8; ++e) {
            a0[e] = (short)f2b(apf[e]);
            a1[e] = (short)f2b(apf[32 + e]);
            a2[e] = (short)f2b(apf[64 + e]);
            a3[e] = (short)f2b(apf[96 + e]);
        }
        apf += 16 * DIM;
        f32x4 acc = *(const f32x4*)&sqh[cb + lg * 4];
        acc = __builtin_amdgcn_mfma_f32_16x16x32_bf16(a0, nb[0], acc, 0, 0, 0);
        acc = __builtin_amdgcn_mfma_f32_16x16x32_bf16(a1, nb[1], acc, 0, 0, 0);
        acc = __builtin_amdgcn_mfma_f32_16x16x32_bf16(a2, nb[2], acc, 0, 0, 0);
        acc = __builtin_amdgcn_mfma_f32_16x16x32_bf16(a3, nb[3], acc, 0, 0, 0);
        #pragma unroll
        for (int r = 0; r < 4; ++r) {
            const float val = acc[r];
            if (val < bv[TSEL6 - 1]) {
                const int jg = cb + lg * 4 + r;
                #pragma unroll
                for (int k = TSEL6 - 1; k >= 1; --k) {
                    const bool m1 = val < bv[k - 1];
                    const bool m2 = val < bv[k];
                    bv[k] = m1 ? bv[k - 1] : (m2 ? val : bv[k]);
                    bi[k] = m1 ? bi[k - 1] : (m2 ? jg  : bi[k]);
                }
                if (val < bv[0]) { bv[0] = val; bi[0] = jg; }
            }
        }
    }
    __syncthreads();
    float4 xi4[32];
    {
        const float4* xr = (const float4*)(X + (size_t)grow * DIM);
        #pragma unroll
        for (int g = 0; g < 32; ++g) xi4[g] = xr[g];
    }
    const float sqi32 = np_sq_avx512(X + (size_t)grow * DIM);
    #pragma unroll
    for (int k = 0; k < TSEL6; ++k) {
        const int j = bi[k];
        unsigned long long key;
        if (j == grow) {
            key = 0xFFFFFFFFFFFFFFFFULL;
        } else {
            const float* xjp = X + (size_t)j * DIM;
            const float4* xj = (const float4*)xjp;
            const float sqj32 = np_sq_avx512(xjp);
            float cacc = 0.f;
            #pragma unroll
            for (int g = 0; g < 32; ++g) {
                const float4 a = xi4[g], b = xj[g];
                cacc = __fmaf_rn(a.x, b.x, cacc);
                cacc = __fmaf_rn(a.y, b.y, cacc);
                cacc = __fmaf_rn(a.z, b.z, cacc);
                cacc = __fmaf_rn(a.w, b.w, cacc);
            }
            float d2c = __fsub_rn(__fadd_rn(sqi32, sqj32),
                                  __fmul_rn(2.0f, cacc));
            if (d2c < 0.0f) d2c = 0.0f;
            const float dist32 = sqrtf(d2c);
            key = ((unsigned long long)__float_as_uint(dist32) << 32)
                  | (unsigned int)j;
        }
        keys[rloc * CSTRIDE + s * TSEL6 + k] = key;
    }
    __syncthreads();
    if (tid < RPB) {
        const int base = tid * CSTRIDE;
        const int i = blockIdx.x * RPB + tid;
        for (int m = 0; m < KSEL; ++m) {
            unsigned long long best = 0xFFFFFFFFFFFFFFFFULL; int bc = 0;
            for (int c2 = 0; c2 < NC; ++c2) {
                const unsigned long long v = keys[base + c2];
                if (v < best) { best = v; bc = c2; }
            }
            out[(size_t)i * KSEL + m] = (int)(best & 0xFFFFFFFFULL);
            keys[base + bc] = 0xFFFFFFFFFFFFFFFFULL;
        }
    }
}

extern "C" void kernel_launch(void* const* d_in, const int* in_sizes, int n_in,
                              void* d_out, int out_size, void* d_ws, size_t ws_size,
                              hipStream_t stream) {
    (void)in_sizes; (void)n_in; (void)out_size;
    const float* X = (const float*)d_in[0];
    int* out = (int*)d_out;
    const size_t sqB   = (size_t)NPTS * 4;                 // 64 KB
    const size_t xbB   = (size_t)NPTS * DIM * 2;           // 4.19 MB
    const size_t candB = (size_t)NPTS * NRC * 2;           // 2.10 MB
    float* sqws = (float*)d_ws;
    unsigned short* Xb = (unsigned short*)((char*)d_ws + sqB);
    unsigned short* candw = (unsigned short*)((char*)d_ws + sqB + xbB);
    if (ws_size >= sqB + xbB + candB) {                    // 6.35 MB
        sq_kernel<<<dim3(NPTS / 256), dim3(256), 0, stream>>>(X, sqws);
        cvt_kernel<<<dim3(NPTS * DIM / 8 / 256), dim3(256), 0, stream>>>(X, Xb);
        scan_q<<<dim3((NPTS / RPB) * NQ), dim3(THREADS), 0, stream>>>(sqws, Xb, candw);
        rescore_f<<<dim3(NPTS / 4), dim3(THREADS), 0, stream>>>(X, candw, out);
    } else if (ws_size >= sqB + xbB) {
        sq_kernel<<<dim3(NPTS / 256), dim3(256), 0, stream>>>(X, sqws);
        cvt_kernel<<<dim3(NPTS * DIM / 8 / 256), dim3(256), 0, stream>>>(X, Xb);
        knn_packed<<<dim3(NPTS / RPB), dim3(THREADS), 0, stream>>>(X, sqws, Xb, out);
    } else {
        knn_mono<<<dim3(NPTS / RPB), dim3(THREADS), 0, stream>>>(X, out);
    }
}